// Round 5
// baseline (816.887 us; speedup 1.0000x reference)
//
#include <hip/hip_runtime.h>
#include <hip/hip_bf16.h>

// ---------------- sentinel & dtype probes ----------------

// Fill d_out (as 16-bit lanes) with 0x3F00: bf16 view = 0.5, fp32 view ~ 0.50006.
__global__ void k_sentinel(unsigned short* __restrict__ out, int n) {
  int i = blockIdx.x * blockDim.x + threadIdx.x;
  if (i < n) out[i] = 0x3F00;
}

// Float dtype probe on v (nonzero ~N(0,1)): for each 32-bit word, low half's
// bf16-exponent field in [115,140] => bf16-like. bf16 data ~99% in band;
// fp32 data ~10%. vflag: 0 = bf16, 1 = fp32.
__global__ void k_ftype(const unsigned* __restrict__ p, int nwords, int* __restrict__ vflag) {
  __shared__ int red[256];
  int ok = 0;
  for (int i = threadIdx.x; i < nwords; i += 256) {
    unsigned lo = p[i] & 0xffffu;
    unsigned ef = (lo >> 7) & 0xffu;
    if (ef >= 115u && ef <= 140u) ok++;
  }
  red[threadIdx.x] = ok;
  __syncthreads();
  for (int s = 128; s > 0; s >>= 1) {
    if (threadIdx.x < s) red[threadIdx.x] += red[threadIdx.x + s];
    __syncthreads();
  }
  if (threadIdx.x == 0) *vflag = (red[0] < nwords / 2) ? 1 : 0;
}

// Edge width probe: int64 => all odd 32-bit words are 0 (values < 2^31).
__global__ void k_etype(const unsigned* __restrict__ p, int nwords, int* __restrict__ eflag) {
  __shared__ unsigned red[256];
  unsigned acc = 0;
  for (int i = threadIdx.x; i < nwords; i += 256)
    if (i & 1) acc |= p[i];
  red[threadIdx.x] = acc;
  __syncthreads();
  for (int s = 128; s > 0; s >>= 1) {
    if (threadIdx.x < s) red[threadIdx.x] |= red[threadIdx.x + s];
    __syncthreads();
  }
  if (threadIdx.x == 0) *eflag = (red[0] == 0u) ? 1 : 0;
}

// ---------------- preprocessing ----------------

__global__ void k_zero(float* __restrict__ deg, int* __restrict__ cnt, int n) {
  int i = blockIdx.x * blockDim.x + threadIdx.x;
  if (i < n) { deg[i] = 0.0f; cnt[i] = 0; }
}

__global__ void k_decode(const void* __restrict__ ei, const int* __restrict__ eflag,
                         int E, int N, int* __restrict__ rowi, int* __restrict__ coli,
                         float* __restrict__ deg, int* __restrict__ cnt) {
  int e = blockIdx.x * blockDim.x + threadIdx.x;
  if (e >= E) return;
  int f = *eflag;
  int r, c;
  if (f) {
    const long long* q = (const long long*)ei;
    r = (int)q[e]; c = (int)q[e + E];
  } else {
    const int* q = (const int*)ei;
    r = q[e]; c = q[e + E];
  }
  r = min(max(r, 0), N - 1);
  c = min(max(c, 0), N - 1);
  rowi[e] = r; coli[e] = c;
  atomicAdd(&deg[r], 1.0f);
  atomicAdd(&cnt[c], 1);
}

__global__ void k_dis(const float* __restrict__ deg, float* __restrict__ dis, int n) {
  int i = blockIdx.x * blockDim.x + threadIdx.x;
  if (i < n) {
    float d = deg[i];
    dis[i] = (d > 0.f) ? rsqrtf(d) : 0.f;
  }
}

// Single-block exclusive scan (256 threads): cnt -> colPtr[1..n], cursor[i]=colPtr[i]
__global__ void k_scan(const int* __restrict__ cnt, int* __restrict__ colPtr,
                       int* __restrict__ cursor, int n) {
  __shared__ int buf[2][256];
  __shared__ int carry;
  int t = threadIdx.x;
  if (t == 0) carry = 0;
  __syncthreads();
  for (int base = 0; base < n; base += 256) {
    int i = base + t;
    int v = (i < n) ? cnt[i] : 0;
    int sel = 0;
    buf[0][t] = v;
    __syncthreads();
    for (int off = 1; off < 256; off <<= 1) {
      int val = buf[sel][t];
      if (t >= off) val += buf[sel][t - off];
      buf[1 - sel][t] = val;
      sel = 1 - sel;
      __syncthreads();
    }
    int incl = carry + buf[sel][t];
    if (i < n) { colPtr[i + 1] = incl; cursor[i] = incl - v; }
    int total = buf[sel][255];
    __syncthreads();
    if (t == 0) carry += total;
    __syncthreads();
  }
  if (t == 0) colPtr[0] = 0;
}

__global__ void k_place(const int* __restrict__ rowi, const int* __restrict__ coli,
                        const float* __restrict__ dis, int* __restrict__ cursor,
                        int* __restrict__ srcRow, float* __restrict__ srcW, int E) {
  int e = blockIdx.x * blockDim.x + threadIdx.x;
  if (e >= E) return;
  int r = rowi[e], c = coli[e];
  float wv = -dis[r] * dis[c];
  int pos = atomicAdd(&cursor[c], 1);
  srcRow[pos] = r;
  srcW[pos] = wv;
}

// v (bf16 or fp32 per vflag) -> fp32 x
__global__ void k_convert(const void* __restrict__ v, const int* __restrict__ vflag,
                          float* __restrict__ x, int n) {
  int i = blockIdx.x * blockDim.x + threadIdx.x;
  if (i >= n) return;
  if (*vflag) x[i] = ((const float*)v)[i];
  else        x[i] = __bfloat162float(((const __hip_bfloat16*)v)[i]);
}

// ---------------- propagation ----------------
// out[c,:] = alpha * sum_{e: col=c} w_e * z[row_e,:] + beta*base[c,:]
__global__ void k_prop(const float* __restrict__ z, const float* __restrict__ base,
                       float* __restrict__ out,
                       const int* __restrict__ colPtr, const int* __restrict__ srcRow,
                       const float* __restrict__ srcW,
                       int F, float alpha, float beta) {
  const int c = blockIdx.x;
  const int f = threadIdx.x;
  const int s = colPtr[c];
  const int e = colPtr[c + 1];
  float acc = 0.f;
  for (int j = s; j < e; j++)
    acc = fmaf(srcW[j], z[(size_t)srcRow[j] * F + f], acc);
  float vv = alpha * acc;
  if (base != nullptr) vv = fmaf(beta, base[(size_t)c * F + f], vv);
  out[(size_t)c * F + f] = vv;
}

// ---------------- GEMM ----------------
// C[N,Fo] = maybe_relu( [A0|A1|A2] @ W + b ); W/bias dtype per wflag (0=bf16,1=fp32).
// Output: outF fp32 workspace, or d_out in input dtype (outB16/outB32).
__global__ void k_gemm(const float* __restrict__ A0, const float* __restrict__ A1,
                       const float* __restrict__ A2,
                       const void* __restrict__ W, const void* __restrict__ bias,
                       const int* __restrict__ wflagp,
                       int N, int Fi, int NQ, int Fo,
                       float* __restrict__ outF, unsigned short* __restrict__ outB16,
                       float* __restrict__ outB32, int relu) {
  __shared__ float As[16][64];
  __shared__ float Bs[16][64];
  const int wflag = *wflagp;
  const int tid = threadIdx.x;
  const int tx = tid & 15, ty = tid >> 4;
  const int m0 = blockIdx.x * 64, n0 = blockIdx.y * 64;
  const int lc = tid & 15, lr = tid >> 4;
  const int bc = tid & 63, br = tid >> 6;
  float acc[4][4];
  for (int i = 0; i < 4; i++)
    for (int j = 0; j < 4; j++) acc[i][j] = 0.f;
  const int K = NQ * Fi;
  for (int k0 = 0; k0 < K; k0 += 16) {
    const int q = k0 / Fi;
    const int kk = k0 - q * Fi;
    const float* A = (q == 0) ? A0 : ((q == 1) ? A1 : A2);
#pragma unroll
    for (int i = 0; i < 4; i++) {
      int row = m0 + lr + i * 16;
      float vv = 0.f;
      if (row < N) vv = A[(size_t)row * Fi + kk + lc];
      As[lc][lr + i * 16] = vv;
    }
#pragma unroll
    for (int i = 0; i < 4; i++) {
      int kr = br + i * 4;
      size_t widx = ((size_t)q * Fi + kk + kr) * Fo + n0 + bc;
      float wv;
      if (wflag) wv = ((const float*)W)[widx];
      else       wv = __bfloat162float(((const __hip_bfloat16*)W)[widx]);
      Bs[kr][bc] = wv;
    }
    __syncthreads();
#pragma unroll
    for (int k = 0; k < 16; k++) {
      float a[4], b[4];
#pragma unroll
      for (int i = 0; i < 4; i++) a[i] = As[k][ty * 4 + i];
#pragma unroll
      for (int j = 0; j < 4; j++) b[j] = Bs[k][tx * 4 + j];
#pragma unroll
      for (int i = 0; i < 4; i++)
#pragma unroll
        for (int j = 0; j < 4; j++)
          acc[i][j] = fmaf(a[i], b[j], acc[i][j]);
    }
    __syncthreads();
  }
#pragma unroll
  for (int i = 0; i < 4; i++) {
    int m = m0 + ty * 4 + i;
    if (m >= N) continue;
#pragma unroll
    for (int j = 0; j < 4; j++) {
      int nn = n0 + tx * 4 + j;
      float bv;
      if (wflag) bv = ((const float*)bias)[nn];
      else       bv = __bfloat162float(((const __hip_bfloat16*)bias)[nn]);
      float vv = acc[i][j] + bv;
      if (relu) vv = fmaxf(vv, 0.f);
      if (outF != nullptr) {
        outF[(size_t)m * Fo + nn] = vv;
      } else if (wflag) {
        outB32[(size_t)m * Fo + nn] = vv;
      } else {
        __hip_bfloat16 h = __float2bfloat16(vv);
        outB16[(size_t)m * Fo + nn] = *(unsigned short*)&h;
      }
    }
  }
}

// ---------------- host (kernel launches ONLY) ----------------

static size_t align256(size_t x) { return (x + 255) & ~(size_t)255; }

extern "C" void kernel_launch(void* const* d_in, const int* in_sizes, int n_in,
                              void* d_out, int out_size, void* d_ws, size_t ws_size,
                              hipStream_t stream) {
  const void* v    = d_in[0];
  const void* ei   = d_in[1];
  const void* W1   = d_in[2];
  const void* b1   = d_in[3];
  const void* W2   = d_in[4];
  const void* b2   = d_in[5];
  const void* W3   = d_in[6];
  const void* b3   = d_in[7];
  const void* Wmu  = d_in[8];
  const void* bmu  = d_in[9];
  const void* Wstd = d_in[10];
  const void* bstd = d_in[11];
  (void)n_in; (void)ws_size;

  const int N = in_sizes[0] / 128;   // 10000
  const int E = in_sizes[1] / 2;     // 160000

  // workspace carve-out
  char* base = (char*)d_ws;
  size_t off = 0;
  int*   eflag;  eflag  = (int*)  (base + off); off = align256(off + 4);
  int*   vflag;  vflag  = (int*)  (base + off); off = align256(off + 4);
  int*   rowi;   rowi   = (int*)  (base + off); off = align256(off + (size_t)E * 4);
  int*   coli;   coli   = (int*)  (base + off); off = align256(off + (size_t)E * 4);
  float* deg;    deg    = (float*)(base + off); off = align256(off + (size_t)N * 4);
  float* dis;    dis    = (float*)(base + off); off = align256(off + (size_t)N * 4);
  int*   cnt;    cnt    = (int*)  (base + off); off = align256(off + (size_t)N * 4);
  int*   colPtr; colPtr = (int*)  (base + off); off = align256(off + (size_t)(N + 1) * 4);
  int*   cursor; cursor = (int*)  (base + off); off = align256(off + (size_t)N * 4);
  int*   srcRow; srcRow = (int*)  (base + off); off = align256(off + (size_t)E * 4);
  float* srcW;   srcW   = (float*)(base + off); off = align256(off + (size_t)E * 4);
  float* xA;     xA     = (float*)(base + off); off = align256(off + (size_t)N * 256 * 4);
  float* xB;     xB     = (float*)(base + off); off = align256(off + (size_t)N * 512 * 4);
  float* tx1;    tx1    = (float*)(base + off); off = align256(off + (size_t)N * 256 * 4);
  float* tx2;    tx2    = (float*)(base + off); off = align256(off + (size_t)N * 256 * 4);

  unsigned short* outMu16  = (unsigned short*)d_out;
  unsigned short* outStd16 = outMu16 + (size_t)N * 256;
  float*          outMu32  = (float*)d_out;
  float*          outStd32 = outMu32 + (size_t)N * 256;

  // 1) sentinel: proves kernels execute at all (overwritten by heads below)
  k_sentinel<<<(out_size + 255) / 256, 256, 0, stream>>>((unsigned short*)d_out, out_size);

  // 2) dtype probes
  k_ftype<<<1, 256, 0, stream>>>((const unsigned*)v, 1024, vflag);
  k_etype<<<1, 256, 0, stream>>>((const unsigned*)ei, 2048, eflag);

  // 3) graph preprocessing
  k_zero<<<(N + 255) / 256, 256, 0, stream>>>(deg, cnt, N);
  k_decode<<<(E + 255) / 256, 256, 0, stream>>>(ei, eflag, E, N, rowi, coli, deg, cnt);
  k_dis<<<(N + 255) / 256, 256, 0, stream>>>(deg, dis, N);
  k_scan<<<1, 256, 0, stream>>>(cnt, colPtr, cursor, N);
  k_place<<<(E + 255) / 256, 256, 0, stream>>>(rowi, coli, dis, cursor, srcRow, srcW, E);
  k_convert<<<(N * 128 + 255) / 256, 256, 0, stream>>>(v, vflag, xA, N * 128);

  const int gM = (N + 63) / 64;

  // layer 1: Fi=128 -> Fo=128, x0=xA -> x1=xB
  k_prop<<<N, 128, 0, stream>>>(xA, nullptr, tx1, colPtr, srcRow, srcW, 128, 1.f, 0.f);
  k_prop<<<N, 128, 0, stream>>>(tx1, xA, tx2, colPtr, srcRow, srcW, 128, 2.f, -1.f);
  k_gemm<<<dim3(gM, 2), 256, 0, stream>>>(xA, tx1, tx2, W1, b1, vflag, N, 128, 3, 128,
                                          xB, nullptr, nullptr, 1);

  // layer 2: Fi=128 -> Fo=256, x1=xB -> x2=xA
  k_prop<<<N, 128, 0, stream>>>(xB, nullptr, tx1, colPtr, srcRow, srcW, 128, 1.f, 0.f);
  k_prop<<<N, 128, 0, stream>>>(tx1, xB, tx2, colPtr, srcRow, srcW, 128, 2.f, -1.f);
  k_gemm<<<dim3(gM, 4), 256, 0, stream>>>(xB, tx1, tx2, W2, b2, vflag, N, 128, 3, 256,
                                          xA, nullptr, nullptr, 1);

  // layer 3: Fi=256 -> Fo=512, x2=xA -> x3=xB
  k_prop<<<N, 256, 0, stream>>>(xA, nullptr, tx1, colPtr, srcRow, srcW, 256, 1.f, 0.f);
  k_prop<<<N, 256, 0, stream>>>(tx1, xA, tx2, colPtr, srcRow, srcW, 256, 2.f, -1.f);
  k_gemm<<<dim3(gM, 8), 256, 0, stream>>>(xA, tx1, tx2, W3, b3, vflag, N, 256, 3, 512,
                                          xB, nullptr, nullptr, 1);

  // heads: x3 (N x 512) @ Wmu/Wstd (512 x 256) -> d_out in detected dtype
  k_gemm<<<dim3(gM, 4), 256, 0, stream>>>(xB, nullptr, nullptr, Wmu, bmu, vflag,
                                          N, 512, 1, 256,
                                          nullptr, outMu16, outMu32, 0);
  k_gemm<<<dim3(gM, 4), 256, 0, stream>>>(xB, nullptr, nullptr, Wstd, bstd, vflag,
                                          N, 512, 1, 256,
                                          nullptr, outStd16, outStd32, 0);
}